// Round 1
// baseline (861.537 us; speedup 1.0000x reference)
//
#include <hip/hip_runtime.h>

// LGA3D ×3 (GANet local guided aggregation), fp32.
// out[c,d,h,w] = sum_{g,i,j} filt[g*25+i*5+j,h,w] * in[c,d+g-1,h+i-2,w+j-2]
// Strategy: per input plane d', compute S0/S1/S2 (25-tap spatial convs with the
// three filter groups) from one LDS-staged tile, roll into out[d'-1],out[d'],out[d'+1]
// with 2 rolling accumulators. Filters (75 floats) live in registers per thread,
// reused across all 48 depth planes.
//
// R1 change (T14 async-STAGE split): staging was load->ds_write adjacent at the top
// of each iteration => full global-load latency exposed before compute every plane.
// Now: issue plane d+2 load into registers at iter top, compute plane d, ds_write
// plane d+1 (loaded last iter, vmcnt long since satisfiable) after compute, barrier.
// Depth-2 prefetch => ~2 compute phases (~700+ cyc) of latency hiding.
// Loop hand-unrolled x2 so staging regs are statically named (no scratch).

namespace {
constexpr int C  = 16, D = 48, H = 128, W = 256;
constexpr int TH = 4, TW = 64;
constexpr int LH = TH + 4;           // 8 tile rows (h0-2 .. h0+TH+1)
constexpr int LW = 72;               // 72 cols: gw = w0-4 .. w0+67 (16B-aligned base)
constexpr int NF = 75;
constexpr int HW = H * W;
constexpr int SLOTS = LH * (LW / 4); // 144 float4 staging slots
}

__global__ __launch_bounds__(256, 4)
void lga_pass(const float* __restrict__ in, const float* __restrict__ filt,
              float* __restrict__ out)
{
    __shared__ float buf[2][LH * LW];

    const int tx = threadIdx.x;       // 0..63  (one wave per ty row)
    const int ty = threadIdx.y;       // 0..3
    const int tid = ty * 64 + tx;
    const int w0 = blockIdx.x * TW;
    const int h0 = blockIdx.y * TH;
    const int c  = blockIdx.z;
    const int h  = h0 + ty;
    const int w  = w0 + tx;

    // ---- filters -> registers (reused for all 48 planes) ----
    float f[NF];
    #pragma unroll
    for (int k = 0; k < NF; ++k)
        f[k] = filt[k * HW + h * W + w];

    // ---- precompute this thread's staging slot (d-invariant) ----
    const bool haveSlot = tid < SLOTS;          // threads 144..255 idle in staging
    const int r  = tid / 18;                    // tile row 0..7
    const int q  = tid - r * 18;                // float4 index in row, 0..17
    const int gh = h0 - 2 + r;
    const int gw = w0 - 4 + 4 * q;              // 16B aligned; OOB all-or-nothing per float4
    const bool valid = haveSlot && (gh >= 0) && (gh < H) && (gw >= 0) && (gw < W);
    const int planeOff = gh * W + gw;
    const int ldsOff   = r * LW + 4 * q;
    const float* planeBase = in + c * (D * HW);

    auto loadPlane = [&](int dp) -> float4 {
        float4 v = make_float4(0.f, 0.f, 0.f, 0.f);
        if (valid && dp < D) v = *(const float4*)(planeBase + dp * HW + planeOff);
        return v;
    };

    // rolling accumulators: a_prev = partial out[d-1], a_cur = partial out[d]
    float a_prev = 0.f, a_cur = 0.f;
    float* outp = out + c * (D * HW) + h * W + w;

    auto computePlane = [&](int d, int bsel) {
        // patch base: buffer row ty = input row h-2; col tx+2 is gw = w-2
        const float* bp = &buf[bsel][ty * LW + tx + 2];
        float s0 = 0.f, s1 = 0.f, s2 = 0.f;
        #pragma unroll
        for (int i = 0; i < 5; ++i) {
            #pragma unroll
            for (int j = 0; j < 5; ++j) {
                float v = bp[i * LW + j];
                s0 = fmaf(f[     i * 5 + j], v, s0);
                s1 = fmaf(f[25 + i * 5 + j], v, s1);
                s2 = fmaf(f[50 + i * 5 + j], v, s2);
            }
        }
        float done = a_prev + s2;          // out[d-1] complete
        if (d > 0) outp[(d - 1) * HW] = done;
        a_prev = a_cur + s1;
        a_cur  = s0;
    };

    // ---- prologue: buf[0] <- plane 0 ; rOdd <- plane 1 (in flight) ----
    float4 rEven, rOdd;
    {
        float4 v0 = loadPlane(0);
        if (haveSlot) *(float4*)(&buf[0][ldsOff]) = v0;
    }
    rOdd = loadPlane(1);
    __syncthreads();

    // ---- main loop: 2 planes per body, one barrier per plane ----
    for (int dd = 0; dd < D; dd += 2) {
        // d = dd (even): compute buf[0], write plane dd+1 -> buf[1]
        rEven = loadPlane(dd + 2);              // issue only; consumed next half
        computePlane(dd, 0);
        if (haveSlot) *(float4*)(&buf[1][ldsOff]) = rOdd;   // waits vmcnt(1)
        __syncthreads();

        // d = dd+1 (odd): compute buf[1], write plane dd+2 -> buf[0]
        rOdd = loadPlane(dd + 3);               // issue only; consumed next half
        computePlane(dd + 1, 1);
        if (haveSlot) *(float4*)(&buf[0][ldsOff]) = rEven;  // waits vmcnt(1)
        __syncthreads();
    }
    outp[(D - 1) * HW] = a_prev;            // out[47] = S0(46)+S1(47)  (S2(48)=0)
}

extern "C" void kernel_launch(void* const* d_in, const int* in_sizes, int n_in,
                              void* d_out, int out_size, void* d_ws, size_t ws_size,
                              hipStream_t stream)
{
    const float* cost = (const float*)d_in[0];
    const float* filt = (const float*)d_in[1];
    float* out = (float*)d_out;

    // scratch for the middle pass: need one full cost-sized buffer
    const size_t needBytes = (size_t)C * D * HW * sizeof(float);
    float* tmp = (ws_size >= needBytes) ? (float*)d_ws : (float*)d_in[0];
    // (fallback writes the input buffer; harness restores d_in before every timed launch)

    dim3 block(64, 4, 1);
    dim3 grid(W / TW, H / TH, C);   // 4 x 32 x 16 = 2048 blocks

    lga_pass<<<grid, block, 0, stream>>>(cost, filt, out);   // pass 1: cost -> out
    lga_pass<<<grid, block, 0, stream>>>(out,  filt, tmp);   // pass 2: out  -> tmp
    lga_pass<<<grid, block, 0, stream>>>(tmp,  filt, out);   // pass 3: tmp  -> out
}

// Round 2
// 393.228 us; speedup vs baseline: 2.1909x; 2.1909x over previous
//
#include <hip/hip_runtime.h>

// LGA3D ×3 (GANet local guided aggregation), fp32.
// out[c,d,h,w] = sum_{g,i,j} filt[g*25+i*5+j,h,w] * in[c,d+g-1,h+i-2,w+j-2]
// Strategy: per input plane d', compute S0/S1/S2 (25-tap spatial convs with the
// three filter groups) from one LDS-staged tile, roll into out[d'-1],out[d'],out[d'+1]
// with 2 rolling accumulators. Filters (75 floats) live in registers per thread,
// reused across all 48 depth planes.
//
// R2: async staging via __builtin_amdgcn_global_load_lds (direct HBM->LDS DMA).
//  - R0 exposed full global-load latency per plane (load -> vmcnt(0) -> ds_write
//    at the top of each iteration, before any compute).
//  - R1 tried register-staged prefetch: +8 live VGPRs -> spills (WRITE_SIZE
//    98->145 MB was scratch traffic), 2.2x regression.
//  - Now: DMA for plane d+1 issued at iteration top, compute plane d overlaps
//    the flight, the compiler's vmcnt(0)-before-barrier drain lands AFTER the
//    compute. Zero extra registers.
//  - DMA constraint (wave-uniform LDS base + lane*16): slot byte addr is
//    exactly tid*16 = ty*1024 + lane*16, so base = &buf[bsel][ty*256].
//  - OOB slots are d-invariant: pre-zero both buffers once, never DMA them.

namespace {
constexpr int C  = 16, D = 48, H = 128, W = 256;
constexpr int TH = 4, TW = 64;
constexpr int LH = TH + 4;           // 8 tile rows (h0-2 .. h0+TH+1)
constexpr int LW = 72;               // 72 cols: gw = w0-4 .. w0+67 (16B-aligned base)
constexpr int NF = 75;
constexpr int HW = H * W;
constexpr int SLOTS = LH * (LW / 4); // 144 float4 staging slots
}

__global__ __launch_bounds__(256, 4)
void lga_pass(const float* __restrict__ in, const float* __restrict__ filt,
              float* __restrict__ out)
{
    __shared__ float buf[2][LH * LW];

    const int tx = threadIdx.x;       // 0..63  (one wave per ty row)
    const int ty = threadIdx.y;       // 0..3
    const int tid = ty * 64 + tx;
    const int w0 = blockIdx.x * TW;
    const int h0 = blockIdx.y * TH;
    const int c  = blockIdx.z;
    const int h  = h0 + ty;
    const int w  = w0 + tx;

    // ---- filters -> registers (reused for all 48 planes) ----
    float f[NF];
    #pragma unroll
    for (int k = 0; k < NF; ++k)
        f[k] = filt[k * HW + h * W + w];

    // ---- staging slot geometry (d-invariant) ----
    const bool haveSlot = tid < SLOTS;          // threads 144..255 idle in staging
    const int r  = tid / 18;                    // tile row 0..7
    const int q  = tid - r * 18;                // float4 index in row, 0..17
    const int gh = h0 - 2 + r;
    const int gw = w0 - 4 + 4 * q;              // 16B aligned; OOB all-or-nothing per float4
    const bool valid = haveSlot && (gh >= 0) && (gh < H) && (gw >= 0) && (gw < W);
    const int planeOff = gh * W + gw;
    const float* planeBase = in + c * (D * HW);

    // ---- pre-zero both buffers: invalid slots must read 0 for all d ----
    for (int k = tid; k < 2 * LH * LW; k += 256)
        (&buf[0][0])[k] = 0.f;
    __syncthreads();   // zeros visible before any DMA overwrites valid slots

    // async DMA: per-lane global addr, wave-uniform LDS base, lane stride 16B
    auto stage = [&](int dp, int bsel) {
        if (valid) {
            __builtin_amdgcn_global_load_lds(
                (const __attribute__((address_space(1))) void*)(planeBase + dp * HW + planeOff),
                (__attribute__((address_space(3))) void*)(&buf[bsel][ty * 256]),
                16, 0, 0);
        }
    };

    stage(0, 0);
    __syncthreads();   // vmcnt drained by compiler before barrier: plane 0 resident

    // rolling accumulators: a_prev = partial out[d-1], a_cur = partial out[d]
    float a_prev = 0.f, a_cur = 0.f;
    float* outp = out + c * (D * HW) + h * W + w;

    for (int d = 0; d < D; ++d) {
        if (d + 1 < D) stage(d + 1, (d + 1) & 1);   // DMA in flight during compute

        // patch base: buffer row ty = input row h-2; col tx+2 is gw = w-2
        const float* bp = &buf[d & 1][ty * LW + tx + 2];
        float s0 = 0.f, s1 = 0.f, s2 = 0.f;
        #pragma unroll
        for (int i = 0; i < 5; ++i) {
            #pragma unroll
            for (int j = 0; j < 5; ++j) {
                float v = bp[i * LW + j];
                s0 = fmaf(f[     i * 5 + j], v, s0);
                s1 = fmaf(f[25 + i * 5 + j], v, s1);
                s2 = fmaf(f[50 + i * 5 + j], v, s2);
            }
        }

        float done = a_prev + s2;          // out[d-1] complete
        if (d > 0) outp[(d - 1) * HW] = done;
        a_prev = a_cur + s1;
        a_cur  = s0;
        __syncthreads();   // vmcnt(0)+barrier: plane d+1 now resident; buffers safe
    }
    outp[(D - 1) * HW] = a_prev;            // out[47] = S0(46)+S1(47)  (S2(48)=0)
}

extern "C" void kernel_launch(void* const* d_in, const int* in_sizes, int n_in,
                              void* d_out, int out_size, void* d_ws, size_t ws_size,
                              hipStream_t stream)
{
    const float* cost = (const float*)d_in[0];
    const float* filt = (const float*)d_in[1];
    float* out = (float*)d_out;

    // scratch for the middle pass: need one full cost-sized buffer
    const size_t needBytes = (size_t)C * D * HW * sizeof(float);
    float* tmp = (ws_size >= needBytes) ? (float*)d_ws : (float*)d_in[0];
    // (fallback writes the input buffer; harness restores d_in before every timed launch)

    dim3 block(64, 4, 1);
    dim3 grid(W / TW, H / TH, C);   // 4 x 32 x 16 = 2048 blocks

    lga_pass<<<grid, block, 0, stream>>>(cost, filt, out);   // pass 1: cost -> out
    lga_pass<<<grid, block, 0, stream>>>(out,  filt, tmp);   // pass 2: out  -> tmp
    lga_pass<<<grid, block, 0, stream>>>(tmp,  filt, out);   // pass 3: tmp  -> out
}